// Round 1
// baseline (198.696 us; speedup 1.0000x reference)
//
#include <hip/hip_runtime.h>
#include <stdint.h>

// PointNet Feature Propagation, MI355X.
// Pipeline:
//  K0: W (f32 [256][320]) -> W1b bf16 [256][64], W2b bf16 [256][256]
//  K1: exact f32 3-NN + inverse-distance weights -> idxw [B][N][8] (3 int idx + 3 f32 w)
//  K2: Zt[b][s][o] = sum_c W2[o][c] * p2[b][c][s]  (bf16 MFMA, output transposed [s][o])
//  K3a: acc = W1 @ p1 (MFMA) + sum_k w_k * Zt[idx_k][:]  -> y bf16 [B][O][N] + BN partials
//  K3b: reduce partials -> scale/bias per channel
//  K3c: out = relu(y*scale + bias)  f32 [B][O][N]

#define B_   16
#define N_   4096
#define S_   1024
#define D1_  64
#define D2_  256
#define OC_  256

typedef __attribute__((ext_vector_type(8))) short bf16x8;
typedef __attribute__((ext_vector_type(4))) float f32x4;

// workspace layout (bytes)
#define IDXW_OFF 0u            // 16*4096*8*4  = 2 MB
#define ZT_OFF   2097152u      // 16*1024*256*4 = 16 MB
#define Y_OFF    18874368u     // 16*256*4096*2 = 32 MB
#define PART_OFF 52428800u     // 1024*256*2*4  = 2 MB
#define SB_OFF   54525952u     // 256*2*4
#define W1B_OFF  54528000u     // 256*64*2
#define W2B_OFF  54560768u     // 256*256*2
#define WS_NEED  54691840u

__device__ __forceinline__ uint16_t f2bf(float f) {
    union { float f; uint32_t u; } v; v.f = f;
    uint32_t r = v.u + 0x7FFFu + ((v.u >> 16) & 1u);   // RNE
    return (uint16_t)(r >> 16);
}
__device__ __forceinline__ float bf2f(uint32_t h) {
    union { uint32_t u; float f; } v; v.u = h << 16;
    return v.f;
}

// ---------------- K0: weight conversion ----------------
__global__ void k0_prep(const float* __restrict__ W,
                        uint16_t* __restrict__ w1b, uint16_t* __restrict__ w2b) {
    int e = blockIdx.x * 256 + threadIdx.x;     // 0..81919
    if (e >= OC_ * 320) return;
    int o = e / 320, c = e % 320;
    uint16_t b = f2bf(W[e]);
    if (c < 64) w1b[o * 64 + c] = b;
    else        w2b[o * 256 + (c - 64)] = b;
}

// ---------------- K1: three_nn (exact f32) ----------------
// sorted-top3 insert: values via fmin/med3, indices via cndmask.
#define INSERT(d, sidx, d0, d1, d2, i0, i1, i2) do {                      \
    bool ca = (d) < (d2); bool cb = (d) < (d1); bool cc = (d) < (d0);     \
    float _n1 = __builtin_amdgcn_fmed3f((d), (d0), (d1));                 \
    float _n2 = __builtin_amdgcn_fmed3f((d), (d1), (d2));                 \
    int _j2 = cb ? (i1) : (ca ? (sidx) : (i2));                           \
    int _j1 = cc ? (i0) : (cb ? (sidx) : (i1));                           \
    i0 = cc ? (sidx) : (i0);                                              \
    d0 = fminf((d), (d0)); d1 = _n1; d2 = _n2; i1 = _j1; i2 = _j2;        \
} while (0)

__global__ void k1_threenn(const float* __restrict__ xyz1,
                           const float* __restrict__ xyz2,
                           int* __restrict__ idxw) {
    __shared__ float4 pts[4 * 257];   // 4 chunks of 256, staggered by 16B to spread banks
    int b  = blockIdx.y;
    int n0 = blockIdx.x * 128;
    int t  = threadIdx.x;

    for (int s = t; s < S_; s += 256) {
        const float* p = xyz2 + ((size_t)b * S_ + s) * 3;
        pts[(s >> 8) * 257 + (s & 255)] = make_float4(p[0], p[1], p[2], 0.f);
    }
    __syncthreads();

    int chunk = t & 3, nidx = t >> 2;           // 64 n per block-half, 4 s-chunks
    int nA = n0 + nidx, nB = nA + 64;
    const float* q1 = xyz1 + ((size_t)b * N_ + nA) * 3;
    const float* q2 = xyz1 + ((size_t)b * N_ + nB) * 3;
    float ax = q1[0], ay = q1[1], az = q1[2];
    float bx = q2[0], by = q2[1], bz = q2[2];

    float A0 = 3.4e38f, A1 = 3.4e38f, A2 = 3.4e38f; int Ai0 = 0, Ai1 = 0, Ai2 = 0;
    float B0 = 3.4e38f, B1 = 3.4e38f, B2 = 3.4e38f; int Bi0 = 0, Bi1 = 0, Bi2 = 0;

    const float4* base = pts + chunk * 257;
    int sbase = chunk * 256;
    #pragma unroll 4
    for (int j = 0; j < 256; j++) {
        float4 q = base[j];
        int s = sbase + j;
        float dx = ax - q.x, dy = ay - q.y, dz = az - q.z;
        float dA = fmaf(dz, dz, fmaf(dy, dy, dx * dx));
        dx = bx - q.x; dy = by - q.y; dz = bz - q.z;
        float dB = fmaf(dz, dz, fmaf(dy, dy, dx * dx));
        INSERT(dA, s, A0, A1, A2, Ai0, Ai1, Ai2);
        INSERT(dB, s, B0, B1, B2, Bi0, Bi1, Bi2);
    }
    // merge 4 chunk-results (lane0-path preserves lower-index tie preference)
    #pragma unroll
    for (int m = 1; m <= 2; m <<= 1) {
        float e0 = __shfl_xor(A0, m), e1 = __shfl_xor(A1, m), e2 = __shfl_xor(A2, m);
        int   g0 = __shfl_xor(Ai0, m), g1 = __shfl_xor(Ai1, m), g2 = __shfl_xor(Ai2, m);
        INSERT(e0, g0, A0, A1, A2, Ai0, Ai1, Ai2);
        INSERT(e1, g1, A0, A1, A2, Ai0, Ai1, Ai2);
        INSERT(e2, g2, A0, A1, A2, Ai0, Ai1, Ai2);
        e0 = __shfl_xor(B0, m); e1 = __shfl_xor(B1, m); e2 = __shfl_xor(B2, m);
        g0 = __shfl_xor(Bi0, m); g1 = __shfl_xor(Bi1, m); g2 = __shfl_xor(Bi2, m);
        INSERT(e0, g0, B0, B1, B2, Bi0, Bi1, Bi2);
        INSERT(e1, g1, B0, B1, B2, Bi0, Bi1, Bi2);
        INSERT(e2, g2, B0, B1, B2, Bi0, Bi1, Bi2);
    }
    if (chunk == 0) {
        float* fw = (float*)idxw;
        {
            float r0 = 1.0f / (A0 + 1e-8f), r1 = 1.0f / (A1 + 1e-8f), r2 = 1.0f / (A2 + 1e-8f);
            float rs = r0 + r1 + r2;
            int base1 = (b * N_ + nA) * 8;
            idxw[base1 + 0] = Ai0; idxw[base1 + 1] = Ai1; idxw[base1 + 2] = Ai2;
            fw[base1 + 4] = r0 / rs; fw[base1 + 5] = r1 / rs; fw[base1 + 6] = r2 / rs;
        }
        {
            float r0 = 1.0f / (B0 + 1e-8f), r1 = 1.0f / (B1 + 1e-8f), r2 = 1.0f / (B2 + 1e-8f);
            float rs = r0 + r1 + r2;
            int base2 = (b * N_ + nB) * 8;
            idxw[base2 + 0] = Bi0; idxw[base2 + 1] = Bi1; idxw[base2 + 2] = Bi2;
            fw[base2 + 4] = r0 / rs; fw[base2 + 5] = r1 / rs; fw[base2 + 6] = r2 / rs;
        }
    }
}

// ---------------- K2: Zt[b][s][o] = sum_c W2[o][c]*p2[b][c][s] ----------------
__global__ void k2_z(const float* __restrict__ p2, const uint16_t* __restrict__ w2b,
                     float* __restrict__ zt) {
    __shared__ uint16_t a_t[64 * 64];    // [s][c] bf16, XOR-swizzled rows (128B)
    __shared__ uint16_t w_t[256 * 64];   // [o][c] bf16, XOR-swizzled rows (128B)
    int b = blockIdx.y, s0 = blockIdx.x * 64;
    int t = threadIdx.x, l = t & 63, w = t >> 6;   // 4 waves

    f32x4 acc[4][4] = {};   // [mi(s)][oj(o)]
    for (int ck = 0; ck < 4; ck++) {
        __syncthreads();
        // stage A chunk: p2[b][ck*64 + c][s0 + s] -> a_t[s][c]
        {
            int sA = w * 16 + (l & 15);
            const float* p2b = p2 + ((size_t)b * D2_ + (size_t)ck * 64) * S_ + s0;
            #pragma unroll
            for (int j = 0; j < 8; j++) {
                int cp = (l >> 4) + 4 * j;
                float lo = p2b[(size_t)(2 * cp) * S_ + sA];
                float hi = p2b[(size_t)(2 * cp + 1) * S_ + sA];
                uint32_t pk = (uint32_t)f2bf(lo) | ((uint32_t)f2bf(hi) << 16);
                int bo = (cp * 4) ^ ((sA & 7) << 4);
                *(uint32_t*)((char*)a_t + sA * 128 + bo) = pk;
            }
        }
        // stage W2 chunk: w2b[o][ck*64 + c] -> w_t[o][c]
        {
            int wp = t & 31, orow0 = t >> 5;
            #pragma unroll 4
            for (int jj = 0; jj < 32; jj++) {
                int o = orow0 + 8 * jj;
                uint32_t v = *(const uint32_t*)(w2b + (size_t)o * 256 + ck * 64 + 2 * wp);
                int bo = (wp * 4) ^ ((o & 7) << 4);
                *(uint32_t*)((char*)w_t + o * 128 + bo) = v;
            }
        }
        __syncthreads();
        #pragma unroll
        for (int ks = 0; ks < 2; ks++) {
            bf16x8 a[4], bb[4];
            int co = ks * 32 + (l >> 4) * 8;
            #pragma unroll
            for (int mi = 0; mi < 4; mi++) {
                int s = mi * 16 + (l & 15);
                int bo = (co * 2) ^ ((s & 7) << 4);
                a[mi] = *(const bf16x8*)((const char*)a_t + s * 128 + bo);
            }
            #pragma unroll
            for (int oj = 0; oj < 4; oj++) {
                int o = w * 64 + oj * 16 + (l & 15);
                int bo = (co * 2) ^ ((o & 7) << 4);
                bb[oj] = *(const bf16x8*)((const char*)w_t + o * 128 + bo);
            }
            #pragma unroll
            for (int mi = 0; mi < 4; mi++)
                #pragma unroll
                for (int oj = 0; oj < 4; oj++)
                    acc[mi][oj] = __builtin_amdgcn_mfma_f32_16x16x32_bf16(
                        a[mi], bb[oj], acc[mi][oj], 0, 0, 0);
        }
    }
    float* ztb = zt + ((size_t)b * S_ + s0) * 256;
    #pragma unroll
    for (int mi = 0; mi < 4; mi++)
        #pragma unroll
        for (int oj = 0; oj < 4; oj++)
            #pragma unroll
            for (int r = 0; r < 4; r++) {
                int sl = mi * 16 + (l >> 4) * 4 + r;
                int o  = w * 64 + oj * 16 + (l & 15);
                ztb[(size_t)sl * 256 + o] = acc[mi][oj][r];
            }
}

// ---------------- K3a: y = W1@p1 + gather(Zt), + BN partials ----------------
__global__ void k3a(const float* __restrict__ p1, const uint16_t* __restrict__ w1b,
                    const int* __restrict__ idxw, const float* __restrict__ zt,
                    uint16_t* __restrict__ y, float* __restrict__ partials) {
    int i = blockIdx.x;
    int b  = (i & 7) + 8 * (i >> 8);      // XCD-affine: blocks of batch b stay on XCD b%8
    int nt = (i >> 3) & 31;
    int n0 = nt * 128;
    int t = threadIdx.x, l = t & 63, w = t >> 6;   // 8 waves
    int ow = w & 3, nw = w >> 2;
    int oW = ow * 64, nW = nw * 64;

    __shared__ uint16_t pt[128 * 64];   // [n][c] bf16, swizzled
    // stage p1 tile transposed
    {
        int nn = w * 16 + (l & 15);
        const float* p1b = p1 + (size_t)b * D1_ * N_ + n0;
        #pragma unroll
        for (int j = 0; j < 8; j++) {
            int cp = (l >> 4) + 4 * j;
            float lo = p1b[(size_t)(2 * cp) * N_ + nn];
            float hi = p1b[(size_t)(2 * cp + 1) * N_ + nn];
            uint32_t pk = (uint32_t)f2bf(lo) | ((uint32_t)f2bf(hi) << 16);
            int bo = (cp * 4) ^ ((nn & 7) << 4);
            *(uint32_t*)((char*)pt + nn * 128 + bo) = pk;
        }
    }
    // A-frags (W1) straight from global (L2-hot, reused across K-steps)
    bf16x8 af[2][4];
    #pragma unroll
    for (int ks = 0; ks < 2; ks++)
        #pragma unroll
        for (int mi = 0; mi < 4; mi++) {
            int o = oW + mi * 16 + (l & 15);
            int k = ks * 32 + (l >> 4) * 8;
            af[ks][mi] = *(const bf16x8*)(w1b + (size_t)o * 64 + k);
        }
    f32x4 acc[4][4] = {};   // [mi(o)][bj(n)]
    __syncthreads();
    #pragma unroll
    for (int ks = 0; ks < 2; ks++) {
        bf16x8 bf[4];
        int co = ks * 32 + (l >> 4) * 8;
        #pragma unroll
        for (int bj = 0; bj < 4; bj++) {
            int nn = nW + bj * 16 + (l & 15);
            int bo = (co * 2) ^ ((nn & 7) << 4);
            bf[bj] = *(const bf16x8*)((const char*)pt + nn * 128 + bo);
        }
        #pragma unroll
        for (int mi = 0; mi < 4; mi++)
            #pragma unroll
            for (int bj = 0; bj < 4; bj++)
                acc[mi][bj] = __builtin_amdgcn_mfma_f32_16x16x32_bf16(
                    af[ks][mi], bf[bj], acc[mi][bj], 0, 0, 0);
    }
    // gather-add from Zt (L2-resident per batch)
    const float* ztb = zt + ((size_t)b << 10) * 256;
    #pragma unroll
    for (int bj = 0; bj < 4; bj++) {
        int nn = n0 + nW + bj * 16 + (l & 15);
        const int* ib = idxw + ((size_t)(b * N_ + nn)) * 8;
        int j0 = ib[0], j1 = ib[1], j2 = ib[2];
        const float* fb = (const float*)ib;
        float w0 = fb[4], w1 = fb[5], w2 = fb[6];
        #pragma unroll
        for (int mi = 0; mi < 4; mi++) {
            int o = oW + mi * 16 + (l >> 4) * 4;
            f32x4 z0 = *(const f32x4*)(ztb + (size_t)j0 * 256 + o);
            f32x4 z1 = *(const f32x4*)(ztb + (size_t)j1 * 256 + o);
            f32x4 z2 = *(const f32x4*)(ztb + (size_t)j2 * 256 + o);
            #pragma unroll
            for (int r = 0; r < 4; r++)
                acc[mi][bj][r] += w0 * z0[r] + w1 * z1[r] + w2 * z2[r];
        }
    }
    // BN partial sums (per o, over this wave's 64 n), reduce over 16 n-lanes
    float s1[4][4], s2v[4][4];
    #pragma unroll
    for (int mi = 0; mi < 4; mi++)
        #pragma unroll
        for (int r = 0; r < 4; r++) {
            float a = 0.f, q = 0.f;
            #pragma unroll
            for (int bj = 0; bj < 4; bj++) { float v = acc[mi][bj][r]; a += v; q += v * v; }
            s1[mi][r] = a; s2v[mi][r] = q;
        }
    #pragma unroll
    for (int m = 1; m <= 8; m <<= 1)
        #pragma unroll
        for (int mi = 0; mi < 4; mi++)
            #pragma unroll
            for (int r = 0; r < 4; r++) {
                s1[mi][r]  += __shfl_xor(s1[mi][r], m);
                s2v[mi][r] += __shfl_xor(s2v[mi][r], m);
            }
    if ((l & 15) == 0) {
        float* ps = partials + ((size_t)(blockIdx.x * 2 + nw)) * 512;
        #pragma unroll
        for (int mi = 0; mi < 4; mi++)
            #pragma unroll
            for (int r = 0; r < 4; r++) {
                int o = oW + mi * 16 + (l >> 4) * 4 + r;
                ps[o * 2 + 0] = s1[mi][r];
                ps[o * 2 + 1] = s2v[mi][r];
            }
    }
    // store y bf16 [B][O][N]
    uint16_t* yb = y + (size_t)b * OC_ * N_;
    #pragma unroll
    for (int mi = 0; mi < 4; mi++)
        #pragma unroll
        for (int bj = 0; bj < 4; bj++)
            #pragma unroll
            for (int r = 0; r < 4; r++) {
                int o  = oW + mi * 16 + (l >> 4) * 4 + r;
                int nn = n0 + nW + bj * 16 + (l & 15);
                yb[(size_t)o * N_ + nn] = f2bf(acc[mi][bj][r]);
            }
}

// ---------------- K3b: finalize BN stats ----------------
__global__ void k3b(const float* __restrict__ partials, const float* __restrict__ gamma,
                    const float* __restrict__ beta, float* __restrict__ sb) {
    int o = blockIdx.x, t = threadIdx.x;
    float a = 0.f, q = 0.f;
    for (int sl = t; sl < 1024; sl += 256) {
        const float* p = partials + (size_t)sl * 512 + o * 2;
        a += p[0]; q += p[1];
    }
    #pragma unroll
    for (int m = 1; m < 64; m <<= 1) { a += __shfl_xor(a, m); q += __shfl_xor(q, m); }
    __shared__ float red[8];
    int w = t >> 6, l = t & 63;
    if (l == 0) { red[w * 2] = a; red[w * 2 + 1] = q; }
    __syncthreads();
    if (t == 0) {
        float A = red[0] + red[2] + red[4] + red[6];
        float Q = red[1] + red[3] + red[5] + red[7];
        float mean = A / 65536.0f;
        float var  = Q / 65536.0f - mean * mean;
        float scale = gamma[o] / sqrtf(var + 1e-5f);
        sb[o * 2] = scale;
        sb[o * 2 + 1] = beta[o] - mean * scale;
    }
}

// ---------------- K3c: normalize + ReLU ----------------
__global__ void k3c(const uint16_t* __restrict__ y, const float* __restrict__ sb,
                    float* __restrict__ out) {
    int g = blockIdx.x * 256 + threadIdx.x;
    size_t e0 = (size_t)g * 32;
    int o = (int)((e0 >> 12) & 255);
    float scale = sb[o * 2], bias = sb[o * 2 + 1];
    const uint4* yp = (const uint4*)(y + e0);
    float4* op = (float4*)(out + e0);
    #pragma unroll
    for (int i = 0; i < 4; i++) {
        uint4 v = yp[i];
        float f0 = bf2f(v.x & 0xffff), f1 = bf2f(v.x >> 16);
        float f2 = bf2f(v.y & 0xffff), f3 = bf2f(v.y >> 16);
        float f4 = bf2f(v.z & 0xffff), f5 = bf2f(v.z >> 16);
        float f6 = bf2f(v.w & 0xffff), f7 = bf2f(v.w >> 16);
        float4 r0, r1;
        r0.x = fmaxf(0.f, fmaf(f0, scale, bias));
        r0.y = fmaxf(0.f, fmaf(f1, scale, bias));
        r0.z = fmaxf(0.f, fmaf(f2, scale, bias));
        r0.w = fmaxf(0.f, fmaf(f3, scale, bias));
        r1.x = fmaxf(0.f, fmaf(f4, scale, bias));
        r1.y = fmaxf(0.f, fmaf(f5, scale, bias));
        r1.z = fmaxf(0.f, fmaf(f6, scale, bias));
        r1.w = fmaxf(0.f, fmaf(f7, scale, bias));
        op[i * 2] = r0;
        op[i * 2 + 1] = r1;
    }
}

extern "C" void kernel_launch(void* const* d_in, const int* in_sizes, int n_in,
                              void* d_out, int out_size, void* d_ws, size_t ws_size,
                              hipStream_t stream) {
    const float* xyz1  = (const float*)d_in[0];
    const float* xyz2  = (const float*)d_in[1];
    const float* p1    = (const float*)d_in[2];
    const float* p2    = (const float*)d_in[3];
    const float* W     = (const float*)d_in[4];
    const float* gamma = (const float*)d_in[5];
    const float* beta  = (const float*)d_in[6];
    float* out = (float*)d_out;
    char* ws = (char*)d_ws;
    if (ws_size < (size_t)WS_NEED) return;   // fail visibly via wrong output

    int*      idxw     = (int*)(ws + IDXW_OFF);
    float*    zt       = (float*)(ws + ZT_OFF);
    uint16_t* y        = (uint16_t*)(ws + Y_OFF);
    float*    partials = (float*)(ws + PART_OFF);
    float*    sb       = (float*)(ws + SB_OFF);
    uint16_t* w1b      = (uint16_t*)(ws + W1B_OFF);
    uint16_t* w2b      = (uint16_t*)(ws + W2B_OFF);

    hipLaunchKernelGGL(k0_prep,    dim3(320),      dim3(256), 0, stream, W, w1b, w2b);
    hipLaunchKernelGGL(k1_threenn, dim3(32, 16),   dim3(256), 0, stream, xyz1, xyz2, idxw);
    hipLaunchKernelGGL(k2_z,       dim3(16, 16),   dim3(256), 0, stream, p2, w2b, zt);
    hipLaunchKernelGGL(k3a,        dim3(512),      dim3(512), 0, stream, p1, w1b, idxw, zt, y, partials);
    hipLaunchKernelGGL(k3b,        dim3(256),      dim3(256), 0, stream, partials, gamma, beta, sb);
    hipLaunchKernelGGL(k3c,        dim3(2048),     dim3(256), 0, stream, y, sb, out);
}

// Round 2
// 182.631 us; speedup vs baseline: 1.0880x; 1.0880x over previous
//
#include <hip/hip_runtime.h>
#include <stdint.h>

// PointNet Feature Propagation, MI355X.
//  K0: W f32 -> W1b bf16 [256][64], W2b bf16 [256][256]
//  K1: exact f32 3-NN + inverse-distance weights -> idxw [B][N][8]
//  K2: Zt[b][s][o] bf16 = W2 @ p2  (MFMA, LDS-transpose epilogue, 512B rows)
//  K3a: acc = W1@p1 (MFMA) + gather(Zt); y stored in fragment-native 128B chunks + BN partials
//  K3b: reduce partials -> per-channel scale/bias
//  K3c: read y chunks coalesced, LDS transpose, BN+ReLU, write f32 out

#define B_   16
#define N_   4096
#define S_   1024
#define D1_  64
#define D2_  256
#define OC_  256

typedef __attribute__((ext_vector_type(8))) short bf16x8;
typedef __attribute__((ext_vector_type(4))) float f32x4;

// workspace layout (bytes)
#define IDXW_OFF 0u            // 2 MB
#define ZT_OFF   2097152u      // 16*1024*256*2 = 8 MB
#define Y_OFF    10485760u     // 16*256*4096*2 = 32 MB (fragment-native)
#define PART_OFF 44040192u     // 1024*512*4 = 2 MB
#define SB_OFF   46137344u     // 2048 B
#define W1B_OFF  46139392u     // 32 KB
#define W2B_OFF  46172160u     // 128 KB
#define WS_NEED  46303232u

__device__ __forceinline__ uint16_t f2bf(float f) {
    union { float f; uint32_t u; } v; v.f = f;
    uint32_t r = v.u + 0x7FFFu + ((v.u >> 16) & 1u);   // RNE
    return (uint16_t)(r >> 16);
}
__device__ __forceinline__ float bf2f(uint32_t h) {
    union { uint32_t u; float f; } v; v.u = h << 16;
    return v.f;
}

// ---------------- K0 ----------------
__global__ void k0_prep(const float* __restrict__ W,
                        uint16_t* __restrict__ w1b, uint16_t* __restrict__ w2b) {
    int e = blockIdx.x * 256 + threadIdx.x;
    if (e >= OC_ * 320) return;
    int o = e / 320, c = e % 320;
    uint16_t b = f2bf(W[e]);
    if (c < 64) w1b[o * 64 + c] = b;
    else        w2b[o * 256 + (c - 64)] = b;
}

// ---------------- K1: three_nn ----------------
#define INSERT(d, sidx, d0, d1, d2, i0, i1, i2) do {                      \
    bool ca = (d) < (d2); bool cb = (d) < (d1); bool cc = (d) < (d0);     \
    float _n1 = __builtin_amdgcn_fmed3f((d), (d0), (d1));                 \
    float _n2 = __builtin_amdgcn_fmed3f((d), (d1), (d2));                 \
    int _j2 = cb ? (i1) : (ca ? (sidx) : (i2));                           \
    int _j1 = cc ? (i0) : (cb ? (sidx) : (i1));                           \
    i0 = cc ? (sidx) : (i0);                                              \
    d0 = fminf((d), (d0)); d1 = _n1; d2 = _n2; i1 = _j1; i2 = _j2;        \
} while (0)

__global__ void k1_threenn(const float* __restrict__ xyz1,
                           const float* __restrict__ xyz2,
                           int* __restrict__ idxw) {
    __shared__ float4 pts[4 * 257];
    int b  = blockIdx.y;
    int n0 = blockIdx.x * 128;
    int t  = threadIdx.x;

    for (int s = t; s < S_; s += 256) {
        const float* p = xyz2 + ((size_t)b * S_ + s) * 3;
        pts[(s >> 8) * 257 + (s & 255)] = make_float4(p[0], p[1], p[2], 0.f);
    }
    __syncthreads();

    int chunk = t & 3, nidx = t >> 2;
    int nA = n0 + nidx, nB = nA + 64;
    const float* q1 = xyz1 + ((size_t)b * N_ + nA) * 3;
    const float* q2 = xyz1 + ((size_t)b * N_ + nB) * 3;
    float ax = q1[0], ay = q1[1], az = q1[2];
    float bx = q2[0], by = q2[1], bz = q2[2];

    float A0 = 3.4e38f, A1 = 3.4e38f, A2 = 3.4e38f; int Ai0 = 0, Ai1 = 0, Ai2 = 0;
    float B0 = 3.4e38f, B1 = 3.4e38f, B2 = 3.4e38f; int Bi0 = 0, Bi1 = 0, Bi2 = 0;

    const float4* base = pts + chunk * 257;
    int sbase = chunk * 256;
    #pragma unroll 4
    for (int j = 0; j < 256; j++) {
        float4 q = base[j];
        int s = sbase + j;
        float dx = ax - q.x, dy = ay - q.y, dz = az - q.z;
        float dA = fmaf(dz, dz, fmaf(dy, dy, dx * dx));
        dx = bx - q.x; dy = by - q.y; dz = bz - q.z;
        float dB = fmaf(dz, dz, fmaf(dy, dy, dx * dx));
        INSERT(dA, s, A0, A1, A2, Ai0, Ai1, Ai2);
        INSERT(dB, s, B0, B1, B2, Bi0, Bi1, Bi2);
    }
    #pragma unroll
    for (int m = 1; m <= 2; m <<= 1) {
        float e0 = __shfl_xor(A0, m), e1 = __shfl_xor(A1, m), e2 = __shfl_xor(A2, m);
        int   g0 = __shfl_xor(Ai0, m), g1 = __shfl_xor(Ai1, m), g2 = __shfl_xor(Ai2, m);
        INSERT(e0, g0, A0, A1, A2, Ai0, Ai1, Ai2);
        INSERT(e1, g1, A0, A1, A2, Ai0, Ai1, Ai2);
        INSERT(e2, g2, A0, A1, A2, Ai0, Ai1, Ai2);
        e0 = __shfl_xor(B0, m); e1 = __shfl_xor(B1, m); e2 = __shfl_xor(B2, m);
        g0 = __shfl_xor(Bi0, m); g1 = __shfl_xor(Bi1, m); g2 = __shfl_xor(Bi2, m);
        INSERT(e0, g0, B0, B1, B2, Bi0, Bi1, Bi2);
        INSERT(e1, g1, B0, B1, B2, Bi0, Bi1, Bi2);
        INSERT(e2, g2, B0, B1, B2, Bi0, Bi1, Bi2);
    }
    if (chunk == 0) {
        float* fw = (float*)idxw;
        {
            float r0 = 1.0f / (A0 + 1e-8f), r1 = 1.0f / (A1 + 1e-8f), r2 = 1.0f / (A2 + 1e-8f);
            float rs = r0 + r1 + r2;
            int base1 = (b * N_ + nA) * 8;
            idxw[base1 + 0] = Ai0; idxw[base1 + 1] = Ai1; idxw[base1 + 2] = Ai2;
            fw[base1 + 4] = r0 / rs; fw[base1 + 5] = r1 / rs; fw[base1 + 6] = r2 / rs;
        }
        {
            float r0 = 1.0f / (B0 + 1e-8f), r1 = 1.0f / (B1 + 1e-8f), r2 = 1.0f / (B2 + 1e-8f);
            float rs = r0 + r1 + r2;
            int base2 = (b * N_ + nB) * 8;
            idxw[base2 + 0] = Bi0; idxw[base2 + 1] = Bi1; idxw[base2 + 2] = Bi2;
            fw[base2 + 4] = r0 / rs; fw[base2 + 5] = r1 / rs; fw[base2 + 6] = r2 / rs;
        }
    }
}

// ---------------- K2: Zt bf16 [b][s][o] ----------------
__global__ void k2_z(const float* __restrict__ p2, const uint16_t* __restrict__ w2b,
                     uint16_t* __restrict__ zt) {
    __shared__ char smem[40960];
    uint16_t* a_t = (uint16_t*)smem;            // [64 s][64 c], 128B rows, swz <<4
    uint16_t* w_t = (uint16_t*)(smem + 8192);   // [256 o][64 c]
    int b = blockIdx.y, s0 = blockIdx.x * 64;
    int t = threadIdx.x, l = t & 63, w = t >> 6;   // 4 waves

    f32x4 acc[4][4] = {};   // [mi(s)][oj(o)]
    for (int ck = 0; ck < 4; ck++) {
        __syncthreads();
        {
            int sA = w * 16 + (l & 15);
            const float* p2b = p2 + ((size_t)b * D2_ + (size_t)ck * 64) * S_ + s0;
            #pragma unroll
            for (int j = 0; j < 8; j++) {
                int cp = (l >> 4) + 4 * j;
                float lo = p2b[(size_t)(2 * cp) * S_ + sA];
                float hi = p2b[(size_t)(2 * cp + 1) * S_ + sA];
                uint32_t pk = (uint32_t)f2bf(lo) | ((uint32_t)f2bf(hi) << 16);
                int bo = (cp * 4) ^ ((sA & 7) << 4);
                *(uint32_t*)((char*)a_t + sA * 128 + bo) = pk;
            }
        }
        {
            int wp = t & 31, orow0 = t >> 5;
            #pragma unroll 4
            for (int jj = 0; jj < 32; jj++) {
                int o = orow0 + 8 * jj;
                uint32_t v = *(const uint32_t*)(w2b + (size_t)o * 256 + ck * 64 + 2 * wp);
                int bo = (wp * 4) ^ ((o & 7) << 4);
                *(uint32_t*)((char*)w_t + o * 128 + bo) = v;
            }
        }
        __syncthreads();
        #pragma unroll
        for (int ks = 0; ks < 2; ks++) {
            bf16x8 a[4], bb[4];
            int co = ks * 32 + (l >> 4) * 8;
            #pragma unroll
            for (int mi = 0; mi < 4; mi++) {
                int s = mi * 16 + (l & 15);
                int bo = (co * 2) ^ ((s & 7) << 4);
                a[mi] = *(const bf16x8*)((const char*)a_t + s * 128 + bo);
            }
            #pragma unroll
            for (int oj = 0; oj < 4; oj++) {
                int o = w * 64 + oj * 16 + (l & 15);
                int bo = (co * 2) ^ ((o & 7) << 4);
                bb[oj] = *(const bf16x8*)((const char*)w_t + o * 128 + bo);
            }
            #pragma unroll
            for (int mi = 0; mi < 4; mi++)
                #pragma unroll
                for (int oj = 0; oj < 4; oj++)
                    acc[mi][oj] = __builtin_amdgcn_mfma_f32_16x16x32_bf16(
                        a[mi], bb[oj], acc[mi][oj], 0, 0, 0);
        }
    }
    // epilogue: transpose via LDS, write 512B rows
    __syncthreads();
    char* tz = smem;   // [64 s][512 B], swz <<5
    #pragma unroll
    for (int mi = 0; mi < 4; mi++)
        #pragma unroll
        for (int oj = 0; oj < 4; oj++)
            #pragma unroll
            for (int r = 0; r < 4; r++) {
                int sl = mi * 16 + (l >> 4) * 4 + r;
                int o  = w * 64 + oj * 16 + (l & 15);
                *(uint16_t*)(tz + sl * 512 + ((o * 2) ^ ((sl & 7) << 5))) = f2bf(acc[mi][oj][r]);
            }
    __syncthreads();
    uint16_t* ztb = zt + ((size_t)b * S_ + s0) * 256;
    #pragma unroll
    for (int k = 0; k < 16; k++) {
        int sl = w * 16 + k;
        #pragma unroll
        for (int h = 0; h < 2; h++) {
            uint32_t v = *(uint32_t*)(tz + sl * 512 + ((h * 256 + l * 4) ^ ((sl & 7) << 5)));
            *(uint32_t*)(ztb + (size_t)sl * 256 + h * 128 + l * 2) = v;
        }
    }
}

// ---------------- K3a ----------------
__global__ void k3a(const float* __restrict__ p1, const uint16_t* __restrict__ w1b,
                    const int* __restrict__ idxw, const uint16_t* __restrict__ zt,
                    uint16_t* __restrict__ y, float* __restrict__ partials) {
    int i = blockIdx.x;                 // 1024, batch-major for Zt L2 residency
    int b = i >> 6, n0 = (i & 63) * 64;
    int t = threadIdx.x, l = t & 63, w = t >> 6;   // 4 waves
    int oW = w * 64;
    __shared__ uint16_t pt[64 * 64];    // [n][c] bf16, 128B rows, swz <<4

    // stage p1 tile transposed
    {
        int nn = t & 63;
        const float* p1b = p1 + (size_t)b * D1_ * N_ + n0;
        #pragma unroll
        for (int j = 0; j < 8; j++) {
            int cp = (t >> 6) + 4 * j;
            float lo = p1b[(size_t)(2 * cp) * N_ + nn];
            float hi = p1b[(size_t)(2 * cp + 1) * N_ + nn];
            uint32_t pk = (uint32_t)f2bf(lo) | ((uint32_t)f2bf(hi) << 16);
            int bo = (cp * 4) ^ ((nn & 7) << 4);
            *(uint32_t*)((char*)pt + nn * 128 + bo) = pk;
        }
    }
    bf16x8 af[2][4];
    #pragma unroll
    for (int ks = 0; ks < 2; ks++)
        #pragma unroll
        for (int mi = 0; mi < 4; mi++) {
            int o = oW + mi * 16 + (l & 15);
            int k = ks * 32 + (l >> 4) * 8;
            af[ks][mi] = *(const bf16x8*)(w1b + (size_t)o * 64 + k);
        }
    f32x4 acc[4][4] = {};   // [mi(o)][bj(n)]
    __syncthreads();
    #pragma unroll
    for (int ks = 0; ks < 2; ks++) {
        bf16x8 bf[4];
        int co = ks * 32 + (l >> 4) * 8;
        #pragma unroll
        for (int bj = 0; bj < 4; bj++) {
            int nn = bj * 16 + (l & 15);
            int bo = (co * 2) ^ ((nn & 7) << 4);
            bf[bj] = *(const bf16x8*)((const char*)pt + nn * 128 + bo);
        }
        #pragma unroll
        for (int mi = 0; mi < 4; mi++)
            #pragma unroll
            for (int bj = 0; bj < 4; bj++)
                acc[mi][bj] = __builtin_amdgcn_mfma_f32_16x16x32_bf16(
                    af[ks][mi], bf[bj], acc[mi][bj], 0, 0, 0);
    }
    // gather-add from bf16 Zt (L2-resident: batch-major ordering)
    const uint16_t* ztb = zt + (size_t)b * S_ * 256;
    #pragma unroll
    for (int bj = 0; bj < 4; bj++) {
        int nn = n0 + bj * 16 + (l & 15);
        const int* ib = idxw + ((size_t)(b * N_ + nn)) * 8;
        int4   iv = *(const int4*)ib;
        float4 wv = *((const float4*)ib + 1);
        #pragma unroll
        for (int mi = 0; mi < 4; mi++) {
            int o = oW + mi * 16 + (l >> 4) * 4;
            uint2 z0 = *(const uint2*)(ztb + (size_t)iv.x * 256 + o);
            uint2 z1 = *(const uint2*)(ztb + (size_t)iv.y * 256 + o);
            uint2 z2 = *(const uint2*)(ztb + (size_t)iv.z * 256 + o);
            acc[mi][bj][0] += wv.x * bf2f(z0.x & 0xffff) + wv.y * bf2f(z1.x & 0xffff) + wv.z * bf2f(z2.x & 0xffff);
            acc[mi][bj][1] += wv.x * bf2f(z0.x >> 16)    + wv.y * bf2f(z1.x >> 16)    + wv.z * bf2f(z2.x >> 16);
            acc[mi][bj][2] += wv.x * bf2f(z0.y & 0xffff) + wv.y * bf2f(z1.y & 0xffff) + wv.z * bf2f(z2.y & 0xffff);
            acc[mi][bj][3] += wv.x * bf2f(z0.y >> 16)    + wv.y * bf2f(z1.y >> 16)    + wv.z * bf2f(z2.y >> 16);
        }
    }
    // BN partial sums
    float s1[4][4], s2v[4][4];
    #pragma unroll
    for (int mi = 0; mi < 4; mi++)
        #pragma unroll
        for (int r = 0; r < 4; r++) {
            float a = 0.f, q = 0.f;
            #pragma unroll
            for (int bj = 0; bj < 4; bj++) { float v = acc[mi][bj][r]; a += v; q += v * v; }
            s1[mi][r] = a; s2v[mi][r] = q;
        }
    #pragma unroll
    for (int m = 1; m <= 8; m <<= 1)
        #pragma unroll
        for (int mi = 0; mi < 4; mi++)
            #pragma unroll
            for (int r = 0; r < 4; r++) {
                s1[mi][r]  += __shfl_xor(s1[mi][r], m);
                s2v[mi][r] += __shfl_xor(s2v[mi][r], m);
            }
    if ((l & 15) == 0) {
        float* ps = partials + (size_t)i * 512;
        #pragma unroll
        for (int mi = 0; mi < 4; mi++)
            #pragma unroll
            for (int r = 0; r < 4; r++) {
                int o = oW + mi * 16 + (l >> 4) * 4 + r;
                ps[o * 2 + 0] = s1[mi][r];
                ps[o * 2 + 1] = s2v[mi][r];
            }
    }
    // store y: fragment-native 128B chunks, fully coalesced
    uint16_t* yb = y + ((size_t)i * 256 + w * 64) * 64 + l;
    #pragma unroll
    for (int mi = 0; mi < 4; mi++)
        #pragma unroll
        for (int bj = 0; bj < 4; bj++)
            #pragma unroll
            for (int r = 0; r < 4; r++)
                yb[(size_t)(mi * 16 + bj * 4 + r) * 64] = f2bf(acc[mi][bj][r]);
}

// ---------------- K3b ----------------
__global__ void k3b(const float* __restrict__ partials, const float* __restrict__ gamma,
                    const float* __restrict__ beta, float* __restrict__ sb) {
    int o = blockIdx.x, t = threadIdx.x;
    float a = 0.f, q = 0.f;
    for (int sl = t; sl < 1024; sl += 256) {
        const float* p = partials + (size_t)sl * 512 + o * 2;
        a += p[0]; q += p[1];
    }
    #pragma unroll
    for (int m = 1; m < 64; m <<= 1) { a += __shfl_xor(a, m); q += __shfl_xor(q, m); }
    __shared__ float red[8];
    int w = t >> 6, l = t & 63;
    if (l == 0) { red[w * 2] = a; red[w * 2 + 1] = q; }
    __syncthreads();
    if (t == 0) {
        float A = red[0] + red[2] + red[4] + red[6];
        float Q = red[1] + red[3] + red[5] + red[7];
        float mean = A / 65536.0f;
        float var  = Q / 65536.0f - mean * mean;
        float scale = gamma[o] / sqrtf(var + 1e-5f);
        sb[o * 2] = scale;
        sb[o * 2 + 1] = beta[o] - mean * scale;
    }
}

// ---------------- K3c: coalesced read, LDS transpose, BN+ReLU ----------------
__global__ void k3c(const uint16_t* __restrict__ y, const float* __restrict__ sb,
                    float* __restrict__ out) {
    __shared__ char ty[32768];          // [256 o][64 n] bf16, 128B rows, swz <<4
    int i = blockIdx.x;                 // 1024
    int b = i >> 6, n0 = (i & 63) * 64;
    int t = threadIdx.x, l = t & 63, w = t >> 6;
    const uint4* yp = (const uint4*)(y + (size_t)i * 16384);
    #pragma unroll
    for (int j = 0; j < 8; j++) {
        int u = j * 256 + t;
        uint4 v = yp[u];
        int chunk = u >> 3, l0 = (u & 7) * 8;
        int cw = chunk >> 6, mi = (chunk >> 4) & 3, bj = (chunk >> 2) & 3, r = chunk & 3;
        int o = cw * 64 + mi * 16 + (l0 >> 4) * 4 + r;
        int n = bj * 16 + (l0 & 15);
        *(uint4*)(ty + o * 128 + ((n * 2) ^ ((o & 7) << 4))) = v;
    }
    __syncthreads();
    int ob = w * 64;
    #pragma unroll 8
    for (int k = 0; k < 64; k++) {
        int o = ob + k;
        float scale = sb[o * 2], bias = sb[o * 2 + 1];
        uint32_t hh = *(const uint16_t*)(ty + o * 128 + ((l * 2) ^ ((o & 7) << 4)));
        float f = bf2f(hh);
        out[((size_t)b * OC_ + o) * N_ + n0 + l] = fmaxf(0.f, fmaf(f, scale, bias));
    }
}

extern "C" void kernel_launch(void* const* d_in, const int* in_sizes, int n_in,
                              void* d_out, int out_size, void* d_ws, size_t ws_size,
                              hipStream_t stream) {
    const float* xyz1  = (const float*)d_in[0];
    const float* xyz2  = (const float*)d_in[1];
    const float* p1    = (const float*)d_in[2];
    const float* p2    = (const float*)d_in[3];
    const float* W     = (const float*)d_in[4];
    const float* gamma = (const float*)d_in[5];
    const float* beta  = (const float*)d_in[6];
    float* out = (float*)d_out;
    char* ws = (char*)d_ws;
    if (ws_size < (size_t)WS_NEED) return;

    int*      idxw     = (int*)(ws + IDXW_OFF);
    uint16_t* zt       = (uint16_t*)(ws + ZT_OFF);
    uint16_t* y        = (uint16_t*)(ws + Y_OFF);
    float*    partials = (float*)(ws + PART_OFF);
    float*    sb       = (float*)(ws + SB_OFF);
    uint16_t* w1b      = (uint16_t*)(ws + W1B_OFF);
    uint16_t* w2b      = (uint16_t*)(ws + W2B_OFF);

    hipLaunchKernelGGL(k0_prep,    dim3(320),    dim3(256), 0, stream, W, w1b, w2b);
    hipLaunchKernelGGL(k1_threenn, dim3(32, 16), dim3(256), 0, stream, xyz1, xyz2, idxw);
    hipLaunchKernelGGL(k2_z,       dim3(16, 16), dim3(256), 0, stream, p2, w2b, zt);
    hipLaunchKernelGGL(k3a,        dim3(1024),   dim3(256), 0, stream, p1, w1b, idxw, zt, y, partials);
    hipLaunchKernelGGL(k3b,        dim3(256),    dim3(256), 0, stream, partials, gamma, beta, sb);
    hipLaunchKernelGGL(k3c,        dim3(1024),   dim3(256), 0, stream, y, sb, out);
}